// Round 4
// baseline (34.895 us; speedup 1.0000x reference)
//
#include <hip/hip_runtime.h>
#include <math.h>

#define OUT_C   384
#define IN_C    384
#define KG      16
#define NUM_IN  16
#define NUM_OUT 16
#define ICH     192   // ic rows per block (half of IN_C)
#define PAD     17    // LDS row stride: 16 taps + circular dup w[16]=w[0]

typedef float floatx4 __attribute__((ext_vector_type(4)));

__global__ __launch_bounds__(256) void gsub_kernel(
    const float* __restrict__ in_H,
    const float* __restrict__ out_H,
    const float* __restrict__ weight,
    float* __restrict__ out)
{
    __shared__ float s_frac[NUM_IN * NUM_OUT];
    __shared__ int   s_i0[NUM_IN * NUM_OUT];
    __shared__ float s_w[ICH * PAD];

    const int t  = threadIdx.x;
    const int b  = blockIdx.x;
    const int oc = b >> 2;
    const int h  = (b >> 1) & 1;
    const int nh = b & 1;                        // ni half: 0 -> ni 0..7, 1 -> 8..15
    const int ic_base = h * ICH;

    // --- per-(ni,no) interpolation params (one pair per thread) ---
    {
        const int ni = t >> 4;
        const int no = t & 15;
        const float TWOPI = 6.283185307179586f;
        float c = in_H[ni] - out_H[no];          // in_H + (-out_H)
        float r = fmodf(c, TWOPI);
        if (r < 0.0f) r += TWOPI;                // jnp.mod semantics
        float pos = r * ((float)KG / TWOPI);
        float bse = floorf(pos);
        s_i0[t]   = ((int)bse) & (KG - 1);
        s_frac[t] = pos - bse;
    }

    // --- stage 192 weight rows into padded LDS; dup tap 0 at slot 16 ---
    const float4* wsrc = (const float4*)(weight + ((size_t)oc * IN_C + ic_base) * KG);
    #pragma unroll
    for (int j = 0; j < 3; ++j) {
        int f = t + j * 256;                     // float4 index 0..767
        float4 v = wsrc[f];
        int ic_l = f >> 2;
        int kq   = (f & 3) * 4;
        float* dst = &s_w[ic_l * PAD + kq];
        dst[0] = v.x; dst[1] = v.y; dst[2] = v.z; dst[3] = v.w;
        if ((f & 3) == 0) s_w[ic_l * PAD + 16] = v.x;   // circular wrap dup
    }
    __syncthreads();

    // --- main loop: thread owns (q = no-quad, lic); wave stores are 1 KB contiguous
    const int q   = t & 3;                       // no-quad 0..3
    const int lic = t >> 2;                      // 0..63

    // out as float4: index = ((oc*16+ni)*384 + ic_base + ic)*4 + q
    floatx4* op = (floatx4*)out + (size_t)oc * 24576 + (size_t)(ic_base + lic) * 4 + q;
    const int fb = 4 * q;
    const int ni0 = nh * 8;

    for (int ni = ni0; ni < ni0 + 8; ++ni) {
        const float* fr = &s_frac[ni * 16 + fb];
        const int*   iz = &s_i0[ni * 16 + fb];
        float f0 = fr[0], f1 = fr[1], f2 = fr[2], f3 = fr[3];
        int   a0 = iz[0], a1 = iz[1], a2 = iz[2], a3 = iz[3];

        #pragma unroll
        for (int r = 0; r < 3; ++r) {
            const float* wrow = &s_w[(r * 64 + lic) * PAD];
            // adjacent pairs (dup at slot 16 avoids mod) -> ds_read2_b32
            float x0 = wrow[a0], y0 = wrow[a0 + 1];
            float x1 = wrow[a1], y1 = wrow[a1 + 1];
            float x2 = wrow[a2], y2 = wrow[a2 + 1];
            float x3 = wrow[a3], y3 = wrow[a3 + 1];
            floatx4 v;
            v.x = fmaf(f0, y0 - x0, x0);
            v.y = fmaf(f1, y1 - x1, x1);
            v.z = fmaf(f2, y2 - x2, x2);
            v.w = fmaf(f3, y3 - x3, x3);
            __builtin_nontemporal_store(v, &op[ni * 1536 + r * 256]);
        }
    }
}

extern "C" void kernel_launch(void* const* d_in, const int* in_sizes, int n_in,
                              void* d_out, int out_size, void* d_ws, size_t ws_size,
                              hipStream_t stream) {
    const float* in_H   = (const float*)d_in[0];
    const float* out_H  = (const float*)d_in[1];
    const float* weight = (const float*)d_in[2];
    float* o = (float*)d_out;
    gsub_kernel<<<OUT_C * 4, 256, 0, stream>>>(in_H, out_H, weight, o);
}

// Round 5
// 30.667 us; speedup vs baseline: 1.1379x; 1.1379x over previous
//
#include <hip/hip_runtime.h>
#include <math.h>

#define OUT_C   384
#define IN_C    384
#define KG      16
#define NUM_IN  16
#define NUM_OUT 16
#define ICH     192   // ic rows per block (half of IN_C)
#define PAD     17    // LDS row stride: 16 taps + circular dup w[16]=w[0]

__global__ __launch_bounds__(256) void gsub_kernel(
    const float* __restrict__ in_H,
    const float* __restrict__ out_H,
    const float* __restrict__ weight,
    float* __restrict__ out)
{
    __shared__ float s_frac[NUM_IN * NUM_OUT];
    __shared__ int   s_i0[NUM_IN * NUM_OUT];
    __shared__ float s_w[ICH * PAD];

    const int t  = threadIdx.x;
    const int b  = blockIdx.x;
    const int oc = b >> 2;
    const int h  = (b >> 1) & 1;
    const int nh = b & 1;                        // ni half: 0 -> ni 0..7, 1 -> 8..15
    const int ic_base = h * ICH;

    // --- per-(ni,no) interpolation params (one pair per thread) ---
    {
        const int ni = t >> 4;
        const int no = t & 15;
        const float TWOPI = 6.283185307179586f;
        float c = in_H[ni] - out_H[no];          // in_H + (-out_H)
        float r = fmodf(c, TWOPI);
        if (r < 0.0f) r += TWOPI;                // jnp.mod semantics
        float pos = r * ((float)KG / TWOPI);
        float bse = floorf(pos);
        s_i0[t]   = ((int)bse) & (KG - 1);
        s_frac[t] = pos - bse;
    }

    // --- stage 192 weight rows into padded LDS; dup tap 0 at slot 16 ---
    const float4* wsrc = (const float4*)(weight + ((size_t)oc * IN_C + ic_base) * KG);
    #pragma unroll
    for (int j = 0; j < 3; ++j) {
        int f = t + j * 256;                     // float4 index 0..767
        float4 v = wsrc[f];
        int ic_l = f >> 2;
        int kq   = (f & 3) * 4;
        float* dst = &s_w[ic_l * PAD + kq];
        dst[0] = v.x; dst[1] = v.y; dst[2] = v.z; dst[3] = v.w;
        if ((f & 3) == 0) s_w[ic_l * PAD + 16] = v.x;   // circular wrap dup
    }
    __syncthreads();

    // --- main loop: thread owns (q = no-quad, lic); wave stores are 1 KB contiguous
    const int q   = t & 3;                       // no-quad 0..3
    const int lic = t >> 2;                      // 0..63

    // out as float4: index = ((oc*16+ni)*384 + ic_base + ic)*4 + q
    float4* op = (float4*)out + (size_t)oc * 24576 + (size_t)(ic_base + lic) * 4 + q;
    const int fb = 4 * q;
    const int ni0 = nh * 8;

    for (int ni = ni0; ni < ni0 + 8; ++ni) {
        const float* fr = &s_frac[ni * 16 + fb];
        const int*   iz = &s_i0[ni * 16 + fb];
        float f0 = fr[0], f1 = fr[1], f2 = fr[2], f3 = fr[3];
        int   a0 = iz[0], a1 = iz[1], a2 = iz[2], a3 = iz[3];

        #pragma unroll
        for (int r = 0; r < 3; ++r) {
            const float* wrow = &s_w[(r * 64 + lic) * PAD];
            // adjacent pairs (dup at slot 16 avoids mod) -> ds_read2_b32
            float x0 = wrow[a0], y0 = wrow[a0 + 1];
            float x1 = wrow[a1], y1 = wrow[a1 + 1];
            float x2 = wrow[a2], y2 = wrow[a2 + 1];
            float x3 = wrow[a3], y3 = wrow[a3 + 1];
            float4 v;
            v.x = fmaf(f0, y0 - x0, x0);
            v.y = fmaf(f1, y1 - x1, x1);
            v.z = fmaf(f2, y2 - x2, x2);
            v.w = fmaf(f3, y3 - x3, x3);
            op[ni * 1536 + r * 256] = v;
        }
    }
}

extern "C" void kernel_launch(void* const* d_in, const int* in_sizes, int n_in,
                              void* d_out, int out_size, void* d_ws, size_t ws_size,
                              hipStream_t stream) {
    const float* in_H   = (const float*)d_in[0];
    const float* out_H  = (const float*)d_in[1];
    const float* weight = (const float*)d_in[2];
    float* o = (float*)d_out;
    gsub_kernel<<<OUT_C * 4, 256, 0, stream>>>(in_H, out_H, weight, o);
}

// Round 6
// 30.149 us; speedup vs baseline: 1.1574x; 1.0172x over previous
//
#include <hip/hip_runtime.h>
#include <math.h>

#define OUT_C   384
#define IN_C    384
#define KG      16
#define NUM_IN  16
#define NUM_OUT 16
#define ICH     192   // ic rows per unit (half of IN_C)
#define PAD     17    // LDS row stride: 16 taps + circular dup w[16]=w[0]
#define UPB     3     // units per block (persistent): 256 blocks x 3 = 768 units

__global__ __launch_bounds__(512) void gsub_kernel(
    const float* __restrict__ in_H,
    const float* __restrict__ out_H,
    const float* __restrict__ weight,
    float* __restrict__ out)
{
    __shared__ float s_frac[NUM_IN * NUM_OUT];
    __shared__ int   s_i0[NUM_IN * NUM_OUT];
    __shared__ float s_w[ICH * PAD];

    const int t = threadIdx.x;

    // --- per-(ni,no) interpolation params: once per block, oc-independent ---
    if (t < 256) {
        const int ni = t >> 4;
        const int no = t & 15;
        const float TWOPI = 6.283185307179586f;
        float c = in_H[ni] - out_H[no];          // in_H + (-out_H)
        float r = fmodf(c, TWOPI);
        if (r < 0.0f) r += TWOPI;                // jnp.mod semantics
        float pos = r * ((float)KG / TWOPI);
        float bse = floorf(pos);
        s_i0[t]   = ((int)bse) & (KG - 1);
        s_frac[t] = pos - bse;
    }

    for (int u0 = 0; u0 < UPB; ++u0) {
        const int unit = blockIdx.x * UPB + u0;   // 0..767, block-contiguous output
        const int oc = unit >> 1;
        const int h  = unit & 1;

        // protect s_w against previous unit's readers (also covers param init)
        __syncthreads();

        // --- stage 192 weight rows (768 float4) into padded LDS ---
        const float4* wsrc = (const float4*)(weight + ((size_t)oc * IN_C + h * ICH) * KG);
        {
            float4 v = wsrc[t];
            int ic_l = t >> 2, kq = (t & 3) * 4;
            float* dst = &s_w[ic_l * PAD + kq];
            dst[0] = v.x; dst[1] = v.y; dst[2] = v.z; dst[3] = v.w;
            if ((t & 3) == 0) s_w[ic_l * PAD + 16] = v.x;   // circular wrap dup
        }
        if (t < 256) {
            int f = 512 + t;
            float4 v = wsrc[f];
            int ic_l = f >> 2, kq = (f & 3) * 4;
            float* dst = &s_w[ic_l * PAD + kq];
            dst[0] = v.x; dst[1] = v.y; dst[2] = v.z; dst[3] = v.w;
            if ((f & 3) == 0) s_w[ic_l * PAD + 16] = v.x;
        }
        __syncthreads();

        // --- store loop: 16 ni x 192 ic x 4 q = 12288 float4 / 512 thr = 24 iters
        // wave-aligned: 768 float4 per ni = 12 waves -> ni is wave-uniform.
        float4* ob = (float4*)out + (size_t)oc * 24576 + (size_t)h * 768;
        #pragma unroll
        for (int i = 0; i < 24; ++i) {
            int f  = i * 512 + t;                // 0..12287
            int ni = f / 768;                    // wave-uniform (const-div)
            int g  = f - ni * 768;               // 0..767
            int lic = g >> 2;
            int qb  = (g & 3) * 4;

            const float* wrow = &s_w[lic * PAD];
            const float* fr   = &s_frac[ni * 16 + qb];
            const int*   iz   = &s_i0[ni * 16 + qb];

            float x0 = wrow[iz[0]], y0 = wrow[iz[0] + 1];
            float x1 = wrow[iz[1]], y1 = wrow[iz[1] + 1];
            float x2 = wrow[iz[2]], y2 = wrow[iz[2] + 1];
            float x3 = wrow[iz[3]], y3 = wrow[iz[3] + 1];
            float4 v;
            v.x = fmaf(fr[0], y0 - x0, x0);
            v.y = fmaf(fr[1], y1 - x1, x1);
            v.z = fmaf(fr[2], y2 - x2, x2);
            v.w = fmaf(fr[3], y3 - x3, x3);
            ob[ni * 1536 + g] = v;
        }
    }
}

extern "C" void kernel_launch(void* const* d_in, const int* in_sizes, int n_in,
                              void* d_out, int out_size, void* d_ws, size_t ws_size,
                              hipStream_t stream) {
    const float* in_H   = (const float*)d_in[0];
    const float* out_H  = (const float*)d_in[1];
    const float* weight = (const float*)d_in[2];
    float* o = (float*)d_out;
    gsub_kernel<<<256, 512, 0, stream>>>(in_H, out_H, weight, o);
}